// Round 3
// 647.373 us; speedup vs baseline: 1.1223x; 1.1223x over previous
//
#include <hip/hip_runtime.h>
#include <hip/hip_bf16.h>
#include <math.h>

// DotProductAttention: B=32, S=2048, D=64 fp32.
// d_out = [O (B*S*D) | W (B*S*S)] fp32.
//
// Round 3 (2nd resubmit after broker timeouts): pre-converted frag-major bf16
// Q/K/V in d_ws + fused one-kernel attention with global_load_lds
// double-buffered staging (one barrier per tile), Q fragments straight from
// global, XCD-swizzled block mapping.
// Falls back to the round-2 verified two-kernel path if ws_size < 24 MiB.

constexpr int BB = 32;
constexpr int SS = 2048;
constexpr int DD = 64;

typedef float  f32x4  __attribute__((ext_vector_type(4)));
typedef __bf16 b16x8  __attribute__((ext_vector_type(8)));

static __device__ __forceinline__ f32x4 mfma16(b16x8 a, b16x8 b, f32x4 c) {
    return __builtin_amdgcn_mfma_f32_16x16x32_bf16(a, b, c, 0, 0, 0);
}

// Async 16B global->LDS (wave-uniform LDS base + lane*16).
static __device__ __forceinline__ void gload16(const __bf16* g, __bf16* l) {
    __builtin_amdgcn_global_load_lds(
        (const __attribute__((address_space(1))) unsigned int*)(const void*)g,
        (__attribute__((address_space(3))) unsigned int*)(void*)l, 16, 0, 0);
}

// Stage a 64x64 fp32 tile (row-major, row stride 64) into frag-major bf16:
// idx(row,d) = ((row>>4)*2 + (d>>5))*512 + (((d>>3)&3)*16 + (row&15))*8 + (d&7)
// -> lane l of frag g holds row=16*(g>>1)+(l&15), d=(g&1)*32+(l>>4)*8+i,
//    i.e. a lane-sequential 16B chunk per fragment (conflict-free b128).
static __device__ __forceinline__ void stage64x64(const float* __restrict__ g,
                                                  __bf16* __restrict__ s, int t) {
    const int row = t >> 2, c0 = (t & 3) * 16;
    const float4* gp = (const float4*)(g + row * 64 + c0);
    float4 f0 = gp[0], f1 = gp[1], f2 = gp[2], f3 = gp[3];
    float v[16] = {f0.x, f0.y, f0.z, f0.w, f1.x, f1.y, f1.z, f1.w,
                   f2.x, f2.y, f2.z, f2.w, f3.x, f3.y, f3.z, f3.w};
    const int base = ((row >> 4) * 2 + (c0 >> 5)) * 512 +
                     (((c0 >> 3) & 3) * 16 + (row & 15)) * 8;
    b16x8 a, b;
#pragma unroll
    for (int i = 0; i < 8; ++i) { a[i] = (__bf16)v[i]; b[i] = (__bf16)v[8 + i]; }
    *(b16x8*)&s[base]       = a;
    *(b16x8*)&s[base + 128] = b;
}

// Stage V 64x64 so PV's B-operand frags are lane-sequential:
// element V[key][d] -> ((d>>4)*2 + (key>>5))*512 + (((key>>3)&3)*16 + (d&15))*8 + (key&7)
static __device__ __forceinline__ void stageV64x64(const float* __restrict__ g,
                                                   __bf16* __restrict__ s, int t) {
    const int key = t >> 2, c0 = (t & 3) * 16;
    const float4* gp = (const float4*)(g + key * 64 + c0);
    float4 f0 = gp[0], f1 = gp[1], f2 = gp[2], f3 = gp[3];
    float v[16] = {f0.x, f0.y, f0.z, f0.w, f1.x, f1.y, f1.z, f1.w,
                   f2.x, f2.y, f2.z, f2.w, f3.x, f3.y, f3.z, f3.w};
    const int base = ((c0 >> 4) * 2 + (key >> 5)) * 512 +
                     (((key >> 3) & 3) * 16) * 8 + (key & 7);
#pragma unroll
    for (int i = 0; i < 16; ++i) s[base + i * 8] = (__bf16)v[i];
}

// ---------------------------------------------------------------------------
// Fast path: one-time conversion of Q/K/V to frag-major bf16 in d_ws.
// One block per (b, 64-row tile); LDS bounce so both global read and global
// write are fully coalesced.
// ---------------------------------------------------------------------------
__global__ __launch_bounds__(256)
void convert_kernel(const float* __restrict__ Q, const float* __restrict__ K,
                    const float* __restrict__ V,
                    __bf16* __restrict__ Qb, __bf16* __restrict__ Kb,
                    __bf16* __restrict__ Vb)
{
    __shared__ __align__(16) __bf16 tmp[4096];
    const int t = threadIdx.x;
    const size_t blk = blockIdx.x;           // b*32 + tile
    const size_t goff = blk * 4096;          // fp32 elements (64*64)

    stage64x64(Q + goff, tmp, t);
    __syncthreads();
    { b16x8 a = *(const b16x8*)&tmp[t * 8], b = *(const b16x8*)&tmp[2048 + t * 8];
      *(b16x8*)(Qb + goff + t * 8) = a; *(b16x8*)(Qb + goff + 2048 + t * 8) = b; }
    __syncthreads();

    stage64x64(K + goff, tmp, t);
    __syncthreads();
    { b16x8 a = *(const b16x8*)&tmp[t * 8], b = *(const b16x8*)&tmp[2048 + t * 8];
      *(b16x8*)(Kb + goff + t * 8) = a; *(b16x8*)(Kb + goff + 2048 + t * 8) = b; }
    __syncthreads();

    stageV64x64(V + goff, tmp, t);
    __syncthreads();
    { b16x8 a = *(const b16x8*)&tmp[t * 8], b = *(const b16x8*)&tmp[2048 + t * 8];
      *(b16x8*)(Vb + goff + t * 8) = a; *(b16x8*)(Vb + goff + 2048 + t * 8) = b; }
}

// ---------------------------------------------------------------------------
// Fused attention: phase 1 = flash-style O + row-sum l (no max subtraction,
// |s| < ~9); phase 2 = recompute QK^T, write W = exp(s)*inv_l; tail fill.
// K/V staged via global_load_lds into double-buffered LDS, 1 barrier/tile.
// ---------------------------------------------------------------------------
__global__ __launch_bounds__(256)
void attn_fused(const __bf16* __restrict__ Qb, const __bf16* __restrict__ Kb,
                const __bf16* __restrict__ Vb, const int* __restrict__ VL,
                float* __restrict__ O, float* __restrict__ W)
{
    __shared__ __align__(16) __bf16 Ks[2][4096], Vs[2][4096];
    __shared__ __align__(16) __bf16 Ps[4][1024];

    const int t = threadIdx.x, lane = t & 63, wave = t >> 6;
    const int quad = lane >> 4, lq = lane & 15;
    // Bijective XCD swizzle (1024 blocks % 8 XCDs == 0): each XCD gets a
    // contiguous chunk of 4 batches -> K/V bf16 working set 2 MB < 4 MB L2.
    const int swz = (blockIdx.x & 7) * 128 + (blockIdx.x >> 3);
    const int b = swz >> 5, qg = swz & 31;

    const int  L    = VL[b];
    const bool uni  = (L == 0);
    const int  Leff = uni ? SS : L;
    const int  ntiles = (Leff + 63) >> 6;

    // Q fragments straight from global (frag-major, 16B/lane coalesced).
    const __bf16* qt = Qb + (size_t)swz * 4096;
    const b16x8 aq0 = *(const b16x8*)(qt + (wave * 2 + 0) * 512 + lane * 8);
    const b16x8 aq1 = *(const b16x8*)(qt + (wave * 2 + 1) * 512 + lane * 8);

    const __bf16* kbase = Kb + (size_t)b * 32 * 4096;
    const __bf16* vbase = Vb + (size_t)b * 32 * 4096;

    auto stageK = [&](int kt, int s) {
        const __bf16* src = kbase + (size_t)kt * 4096;
        gload16(src + wave * 512 + lane * 8,        &Ks[s][wave * 512]);
        gload16(src + 2048 + wave * 512 + lane * 8, &Ks[s][2048 + wave * 512]);
    };
    auto stageV = [&](int kt, int s) {
        const __bf16* src = vbase + (size_t)kt * 4096;
        gload16(src + wave * 512 + lane * 8,        &Vs[s][wave * 512]);
        gload16(src + 2048 + wave * 512 + lane * 8, &Vs[s][2048 + wave * 512]);
    };

    // ---- Phase 1: O + l ----
    f32x4 o[4];
#pragma unroll
    for (int d = 0; d < 4; ++d) o[d] = (f32x4){0.f, 0.f, 0.f, 0.f};
    float lp[4] = {0.f, 0.f, 0.f, 0.f};

    int buf = 0;
    stageK(0, 0); stageV(0, 0);
    __syncthreads();                       // drains vmcnt: tile 0 ready

    for (int kt = 0; kt < ntiles; ++kt) {
        if (kt + 1 < ntiles) { stageK(kt + 1, buf ^ 1); stageV(kt + 1, buf ^ 1); }

#pragma unroll
        for (int ct = 0; ct < 4; ++ct) {
            f32x4 c = (f32x4){0.f, 0.f, 0.f, 0.f};
            c = mfma16(aq0, *(const b16x8*)&Ks[buf][(ct * 2 + 0) * 512 + lane * 8], c);
            c = mfma16(aq1, *(const b16x8*)&Ks[buf][(ct * 2 + 1) * 512 + lane * 8], c);
            const int key = kt * 64 + ct * 16 + lq;
#pragma unroll
            for (int r = 0; r < 4; ++r) {
                float w = uni ? 1.0f : __expf(c[r] * 0.125f);
                w = (key < Leff) ? w : 0.0f;
                lp[r] += w;
                // P element (q=quad*4+r, k=ct*16+lq) -> A-frag layout
                Ps[wave][(ct >> 1) * 512 +
                         (((ct * 2 + (lq >> 3)) & 3) * 16 + quad * 4 + r) * 8 +
                         (lq & 7)] = (__bf16)w;
            }
        }
        // Ps is per-wave: in-wave lgkmcnt ordering suffices, no barrier.
        const b16x8 ap0 = *(const b16x8*)&Ps[wave][0   + lane * 8];
        const b16x8 ap1 = *(const b16x8*)&Ps[wave][512 + lane * 8];
#pragma unroll
        for (int ds = 0; ds < 4; ++ds) {
            o[ds] = mfma16(ap0, *(const b16x8*)&Vs[buf][(ds * 2 + 0) * 512 + lane * 8], o[ds]);
            o[ds] = mfma16(ap1, *(const b16x8*)&Vs[buf][(ds * 2 + 1) * 512 + lane * 8], o[ds]);
        }
        __syncthreads();                   // t+1 loads landed; buf reusable
        buf ^= 1;
    }

    float inv[4];
#pragma unroll
    for (int r = 0; r < 4; ++r) {
        float l = lp[r];
        l += __shfl_xor(l, 1); l += __shfl_xor(l, 2);
        l += __shfl_xor(l, 4); l += __shfl_xor(l, 8);
        inv[r] = 1.0f / l;
    }

    const int qrow = qg * 64 + wave * 16 + quad * 4;
#pragma unroll
    for (int ds = 0; ds < 4; ++ds)
#pragma unroll
        for (int r = 0; r < 4; ++r)
            O[((size_t)b * SS + qrow + r) * DD + ds * 16 + lq] = o[ds][r] * inv[r];

    // ---- Phase 2: W ----
    const int  nt2   = uni ? 0 : ntiles;
    const int  kfill = nt2 * 64;
    const float fillv = uni ? (1.0f / 2048.0f) : 0.0f;

    if (nt2 > 0) {
        buf = 0;
        stageK(0, 0);
        __syncthreads();
        for (int kt = 0; kt < nt2; ++kt) {
            if (kt + 1 < nt2) stageK(kt + 1, buf ^ 1);
#pragma unroll
            for (int ct = 0; ct < 4; ++ct) {
                f32x4 c = (f32x4){0.f, 0.f, 0.f, 0.f};
                c = mfma16(aq0, *(const b16x8*)&Ks[buf][(ct * 2 + 0) * 512 + lane * 8], c);
                c = mfma16(aq1, *(const b16x8*)&Ks[buf][(ct * 2 + 1) * 512 + lane * 8], c);
                const int key = kt * 64 + ct * 16 + lq;
#pragma unroll
                for (int r = 0; r < 4; ++r) {
                    float w = __expf(c[r] * 0.125f) * inv[r];
                    w = (key < L) ? w : 0.0f;
                    W[((size_t)b * SS + qrow + r) * SS + key] = w;
                }
            }
            __syncthreads();
            buf ^= 1;
        }
    }

    // fill masked tail [kfill, 2048) with fillv
    for (int row = 0; row < 64; ++row) {
        float* base = W + ((size_t)b * SS + qg * 64 + row) * SS;
        for (int c = kfill + t * 4; c < SS; c += 1024)
            *(float4*)(base + c) = make_float4(fillv, fillv, fillv, fillv);
    }
}

// ---------------------------------------------------------------------------
// Fallback path (ws too small): round-2 verified two-kernel design, verbatim.
// ---------------------------------------------------------------------------
__global__ __launch_bounds__(256)
void attn_o_kernel(const float* __restrict__ Q, const float* __restrict__ K,
                   const float* __restrict__ V, const int* __restrict__ VL,
                   float* __restrict__ O, float* __restrict__ W)
{
    __shared__ __align__(16) __bf16 Qs[4096], Ks[4096], Vs[4096];
    __shared__ __align__(16) __bf16 Ps[4][1024];

    const int t = threadIdx.x, lane = t & 63, wave = t >> 6;
    const int quad = lane >> 4, lq = lane & 15;
    const int b = blockIdx.x >> 5, qg = blockIdx.x & 31;

    const int  L    = VL[b];
    const bool uni  = (L == 0);
    const int  Leff = uni ? SS : L;
    const int  ntiles = (Leff + 63) >> 6;

    stage64x64(Q + ((size_t)b * SS + qg * 64) * DD, Qs, t);
    __syncthreads();

    const b16x8 aq0 = *(const b16x8*)&Qs[(wave * 2 + 0) * 512 + lane * 8];
    const b16x8 aq1 = *(const b16x8*)&Qs[(wave * 2 + 1) * 512 + lane * 8];

    f32x4 o[4];
#pragma unroll
    for (int d = 0; d < 4; ++d) o[d] = (f32x4){0.f, 0.f, 0.f, 0.f};
    float lp[4] = {0.f, 0.f, 0.f, 0.f};

    for (int kt = 0; kt < ntiles; ++kt) {
        const int kb = kt * 64;
        __syncthreads();
        stage64x64 (K + ((size_t)b * SS + kb) * DD, Ks, t);
        stageV64x64(V + ((size_t)b * SS + kb) * DD, Vs, t);
        __syncthreads();

#pragma unroll
        for (int ct = 0; ct < 4; ++ct) {
            f32x4 c = (f32x4){0.f, 0.f, 0.f, 0.f};
            c = mfma16(aq0, *(const b16x8*)&Ks[(ct * 2 + 0) * 512 + lane * 8], c);
            c = mfma16(aq1, *(const b16x8*)&Ks[(ct * 2 + 1) * 512 + lane * 8], c);
            const int key = kb + ct * 16 + lq;
#pragma unroll
            for (int r = 0; r < 4; ++r) {
                float w = uni ? 1.0f : __expf(c[r] * 0.125f);
                w = (key < Leff) ? w : 0.0f;
                lp[r] += w;
                Ps[wave][(ct >> 1) * 512 +
                         (((ct * 2 + (lq >> 3)) & 3) * 16 + quad * 4 + r) * 8 +
                         (lq & 7)] = (__bf16)w;
            }
        }
        __syncthreads();

        const b16x8 ap0 = *(const b16x8*)&Ps[wave][0   + lane * 8];
        const b16x8 ap1 = *(const b16x8*)&Ps[wave][512 + lane * 8];
#pragma unroll
        for (int ds = 0; ds < 4; ++ds) {
            o[ds] = mfma16(ap0, *(const b16x8*)&Vs[(ds * 2 + 0) * 512 + lane * 8], o[ds]);
            o[ds] = mfma16(ap1, *(const b16x8*)&Vs[(ds * 2 + 1) * 512 + lane * 8], o[ds]);
        }
    }

    float inv[4];
#pragma unroll
    for (int r = 0; r < 4; ++r) {
        float l = lp[r];
        l += __shfl_xor(l, 1); l += __shfl_xor(l, 2);
        l += __shfl_xor(l, 4); l += __shfl_xor(l, 8);
        inv[r] = 1.0f / l;
    }

    const int qrow = qg * 64 + wave * 16 + quad * 4;
#pragma unroll
    for (int ds = 0; ds < 4; ++ds)
#pragma unroll
        for (int r = 0; r < 4; ++r)
            O[((size_t)b * SS + qrow + r) * DD + ds * 16 + lq] = o[ds][r] * inv[r];

    if (lq == 0) {
#pragma unroll
        for (int r = 0; r < 4; ++r)
            W[((size_t)b * SS + qrow + r) * SS + (SS - 1)] = inv[r];
    }
}

__global__ __launch_bounds__(256)
void attn_w_kernel(const float* __restrict__ Q, const float* __restrict__ K,
                   const int* __restrict__ VL, float* __restrict__ W)
{
    __shared__ __align__(16) __bf16 Qs[4096], Ks[4096];

    const int t = threadIdx.x, lane = t & 63, wave = t >> 6;
    const int quad = lane >> 4, lq = lane & 15;
    const int b = blockIdx.x >> 5, qg = blockIdx.x & 31;

    const int  L   = VL[b];
    const bool uni = (L == 0);
    const int  ntiles = uni ? 0 : (L + 63) >> 6;
    const int  kfill  = ntiles * 64;
    const float fillv = uni ? (1.0f / 2048.0f) : 0.0f;
    const int  qrow = qg * 64 + wave * 16 + quad * 4;

    float inv[4] = {0.f, 0.f, 0.f, 0.f};
    if (!uni) {
#pragma unroll
        for (int r = 0; r < 4; ++r)
            inv[r] = W[((size_t)b * SS + qrow + r) * SS + (SS - 1)];
    }

    stage64x64(Q + ((size_t)b * SS + qg * 64) * DD, Qs, t);
    __syncthreads();

    const b16x8 aq0 = *(const b16x8*)&Qs[(wave * 2 + 0) * 512 + lane * 8];
    const b16x8 aq1 = *(const b16x8*)&Qs[(wave * 2 + 1) * 512 + lane * 8];

    for (int kt = 0; kt < ntiles; ++kt) {
        const int kb = kt * 64;
        __syncthreads();
        stage64x64(K + ((size_t)b * SS + kb) * DD, Ks, t);
        __syncthreads();

#pragma unroll
        for (int ct = 0; ct < 4; ++ct) {
            f32x4 c = (f32x4){0.f, 0.f, 0.f, 0.f};
            c = mfma16(aq0, *(const b16x8*)&Ks[(ct * 2 + 0) * 512 + lane * 8], c);
            c = mfma16(aq1, *(const b16x8*)&Ks[(ct * 2 + 1) * 512 + lane * 8], c);
            const int key = kb + ct * 16 + lq;
#pragma unroll
            for (int r = 0; r < 4; ++r) {
                float w = __expf(c[r] * 0.125f) * inv[r];
                w = (key < L) ? w : 0.0f;
                W[((size_t)b * SS + qrow + r) * SS + key] = w;
            }
        }
    }

    for (int row = 0; row < 64; ++row) {
        float* base = W + ((size_t)b * SS + qg * 64 + row) * SS;
        for (int c = kfill + t * 4; c < SS; c += 1024)
            *(float4*)(base + c) = make_float4(fillv, fillv, fillv, fillv);
    }
}

extern "C" void kernel_launch(void* const* d_in, const int* in_sizes, int n_in,
                              void* d_out, int out_size, void* d_ws, size_t ws_size,
                              hipStream_t stream) {
    const float* Q  = (const float*)d_in[0];
    const float* K  = (const float*)d_in[1];
    const float* V  = (const float*)d_in[2];
    const int*   VL = (const int*)d_in[3];
    float* O = (float*)d_out;
    float* W = (float*)d_out + (size_t)BB * SS * DD;

    const size_t nElem = (size_t)BB * SS * DD;          // 4,194,304
    const size_t need  = nElem * 2 * 3;                 // 24 MiB bf16 Q/K/V

    if (d_ws != nullptr && ws_size >= need) {
        __bf16* Qb = (__bf16*)d_ws;
        __bf16* Kb = Qb + nElem;
        __bf16* Vb = Kb + nElem;
        dim3 grid(BB * (SS / 64)), block(256);
        convert_kernel<<<grid, block, 0, stream>>>(Q, K, V, Qb, Kb, Vb);
        attn_fused<<<grid, block, 0, stream>>>(Qb, Kb, Vb, VL, O, W);
    } else {
        dim3 grid(BB * (SS / 64)), block(256);
        attn_o_kernel<<<grid, block, 0, stream>>>(Q, K, V, VL, O, W);
        attn_w_kernel<<<grid, block, 0, stream>>>(Q, K, VL, W);
    }
}

// Round 5
// 633.042 us; speedup vs baseline: 1.1477x; 1.0226x over previous
//
#include <hip/hip_runtime.h>
#include <hip/hip_bf16.h>
#include <math.h>

// DotProductAttention: B=32, S=2048, D=64 fp32.
// d_out = [O (B*S*D) | W (B*S*S)] fp32.
//
// Round 5 (round-4 compile fix: __builtin_nontemporal_store needs a clang
// ext-vector pointer, not HIP float4*): transposed phase-2 (S^T = mfma(K,Q))
// so each lane owns 4 consecutive keys of one W row -> f32x4 nontemporal
// stores (4x fewer store instrs, perfect 16B/lane coalescing). inv
// rebroadcast lq-indexed via per-wave LDS stash. Everything else identical
// to round 3 (verified 647us): pre-converted frag-major bf16 Q/K/V in d_ws,
// fused kernel with global_load_lds double-buffered staging, XCD-swizzled
// block mapping. Falls back to round-2 verified path if ws_size < 24 MiB.

constexpr int BB = 32;
constexpr int SS = 2048;
constexpr int DD = 64;

typedef float  f32x4  __attribute__((ext_vector_type(4)));
typedef __bf16 b16x8  __attribute__((ext_vector_type(8)));

static __device__ __forceinline__ f32x4 mfma16(b16x8 a, b16x8 b, f32x4 c) {
    return __builtin_amdgcn_mfma_f32_16x16x32_bf16(a, b, c, 0, 0, 0);
}

// Async 16B global->LDS (wave-uniform LDS base + lane*16).
static __device__ __forceinline__ void gload16(const __bf16* g, __bf16* l) {
    __builtin_amdgcn_global_load_lds(
        (const __attribute__((address_space(1))) unsigned int*)(const void*)g,
        (__attribute__((address_space(3))) unsigned int*)(void*)l, 16, 0, 0);
}

// Stage a 64x64 fp32 tile (row-major, row stride 64) into frag-major bf16:
// idx(row,d) = ((row>>4)*2 + (d>>5))*512 + (((d>>3)&3)*16 + (row&15))*8 + (d&7)
// -> lane l of frag g holds row=16*(g>>1)+(l&15), d=(g&1)*32+(l>>4)*8+i,
//    i.e. a lane-sequential 16B chunk per fragment (conflict-free b128).
static __device__ __forceinline__ void stage64x64(const float* __restrict__ g,
                                                  __bf16* __restrict__ s, int t) {
    const int row = t >> 2, c0 = (t & 3) * 16;
    const float4* gp = (const float4*)(g + row * 64 + c0);
    float4 f0 = gp[0], f1 = gp[1], f2 = gp[2], f3 = gp[3];
    float v[16] = {f0.x, f0.y, f0.z, f0.w, f1.x, f1.y, f1.z, f1.w,
                   f2.x, f2.y, f2.z, f2.w, f3.x, f3.y, f3.z, f3.w};
    const int base = ((row >> 4) * 2 + (c0 >> 5)) * 512 +
                     (((c0 >> 3) & 3) * 16 + (row & 15)) * 8;
    b16x8 a, b;
#pragma unroll
    for (int i = 0; i < 8; ++i) { a[i] = (__bf16)v[i]; b[i] = (__bf16)v[8 + i]; }
    *(b16x8*)&s[base]       = a;
    *(b16x8*)&s[base + 128] = b;
}

// Stage V 64x64 so PV's B-operand frags are lane-sequential:
// element V[key][d] -> ((d>>4)*2 + (key>>5))*512 + (((key>>3)&3)*16 + (d&15))*8 + (key&7)
static __device__ __forceinline__ void stageV64x64(const float* __restrict__ g,
                                                   __bf16* __restrict__ s, int t) {
    const int key = t >> 2, c0 = (t & 3) * 16;
    const float4* gp = (const float4*)(g + key * 64 + c0);
    float4 f0 = gp[0], f1 = gp[1], f2 = gp[2], f3 = gp[3];
    float v[16] = {f0.x, f0.y, f0.z, f0.w, f1.x, f1.y, f1.z, f1.w,
                   f2.x, f2.y, f2.z, f2.w, f3.x, f3.y, f3.z, f3.w};
    const int base = ((c0 >> 4) * 2 + (key >> 5)) * 512 +
                     (((key >> 3) & 3) * 16) * 8 + (key & 7);
#pragma unroll
    for (int i = 0; i < 16; ++i) s[base + i * 8] = (__bf16)v[i];
}

// ---------------------------------------------------------------------------
// Fast path: one-time conversion of Q/K/V to frag-major bf16 in d_ws.
// ---------------------------------------------------------------------------
__global__ __launch_bounds__(256)
void convert_kernel(const float* __restrict__ Q, const float* __restrict__ K,
                    const float* __restrict__ V,
                    __bf16* __restrict__ Qb, __bf16* __restrict__ Kb,
                    __bf16* __restrict__ Vb)
{
    __shared__ __align__(16) __bf16 tmp[4096];
    const int t = threadIdx.x;
    const size_t blk = blockIdx.x;           // b*32 + tile
    const size_t goff = blk * 4096;          // fp32 elements (64*64)

    stage64x64(Q + goff, tmp, t);
    __syncthreads();
    { b16x8 a = *(const b16x8*)&tmp[t * 8], b = *(const b16x8*)&tmp[2048 + t * 8];
      *(b16x8*)(Qb + goff + t * 8) = a; *(b16x8*)(Qb + goff + 2048 + t * 8) = b; }
    __syncthreads();

    stage64x64(K + goff, tmp, t);
    __syncthreads();
    { b16x8 a = *(const b16x8*)&tmp[t * 8], b = *(const b16x8*)&tmp[2048 + t * 8];
      *(b16x8*)(Kb + goff + t * 8) = a; *(b16x8*)(Kb + goff + 2048 + t * 8) = b; }
    __syncthreads();

    stageV64x64(V + goff, tmp, t);
    __syncthreads();
    { b16x8 a = *(const b16x8*)&tmp[t * 8], b = *(const b16x8*)&tmp[2048 + t * 8];
      *(b16x8*)(Vb + goff + t * 8) = a; *(b16x8*)(Vb + goff + 2048 + t * 8) = b; }
}

// ---------------------------------------------------------------------------
// Fused attention: phase 1 = flash-style O + row-sum l (no max subtraction,
// |s| < ~9); phase 2 = recompute S^T via mfma(K,Q), write W = exp(s)*inv_l
// with f32x4 nontemporal stores; tail fill.
// ---------------------------------------------------------------------------
__global__ __launch_bounds__(256)
void attn_fused(const __bf16* __restrict__ Qb, const __bf16* __restrict__ Kb,
                const __bf16* __restrict__ Vb, const int* __restrict__ VL,
                float* __restrict__ O, float* __restrict__ W)
{
    __shared__ __align__(16) __bf16 Ks[2][4096], Vs[2][4096];
    __shared__ __align__(16) __bf16 Ps[4][1024];

    const int t = threadIdx.x, lane = t & 63, wave = t >> 6;
    const int quad = lane >> 4, lq = lane & 15;
    // Bijective XCD swizzle (1024 blocks % 8 XCDs == 0): each XCD gets a
    // contiguous chunk of 4 batches -> K/V bf16 working set 2 MB < 4 MB L2.
    const int swz = (blockIdx.x & 7) * 128 + (blockIdx.x >> 3);
    const int b = swz >> 5, qg = swz & 31;

    const int  L    = VL[b];
    const bool uni  = (L == 0);
    const int  Leff = uni ? SS : L;
    const int  ntiles = (Leff + 63) >> 6;

    // Q fragments straight from global (frag-major, 16B/lane coalesced).
    const __bf16* qt = Qb + (size_t)swz * 4096;
    const b16x8 aq0 = *(const b16x8*)(qt + (wave * 2 + 0) * 512 + lane * 8);
    const b16x8 aq1 = *(const b16x8*)(qt + (wave * 2 + 1) * 512 + lane * 8);

    const __bf16* kbase = Kb + (size_t)b * 32 * 4096;
    const __bf16* vbase = Vb + (size_t)b * 32 * 4096;

    auto stageK = [&](int kt, int s) {
        const __bf16* src = kbase + (size_t)kt * 4096;
        gload16(src + wave * 512 + lane * 8,        &Ks[s][wave * 512]);
        gload16(src + 2048 + wave * 512 + lane * 8, &Ks[s][2048 + wave * 512]);
    };
    auto stageV = [&](int kt, int s) {
        const __bf16* src = vbase + (size_t)kt * 4096;
        gload16(src + wave * 512 + lane * 8,        &Vs[s][wave * 512]);
        gload16(src + 2048 + wave * 512 + lane * 8, &Vs[s][2048 + wave * 512]);
    };

    // ---- Phase 1: O + l ----
    f32x4 o[4];
#pragma unroll
    for (int d = 0; d < 4; ++d) o[d] = (f32x4){0.f, 0.f, 0.f, 0.f};
    float lp[4] = {0.f, 0.f, 0.f, 0.f};

    int buf = 0;
    stageK(0, 0); stageV(0, 0);
    __syncthreads();                       // drains vmcnt: tile 0 ready

    for (int kt = 0; kt < ntiles; ++kt) {
        if (kt + 1 < ntiles) { stageK(kt + 1, buf ^ 1); stageV(kt + 1, buf ^ 1); }

#pragma unroll
        for (int ct = 0; ct < 4; ++ct) {
            f32x4 c = (f32x4){0.f, 0.f, 0.f, 0.f};
            c = mfma16(aq0, *(const b16x8*)&Ks[buf][(ct * 2 + 0) * 512 + lane * 8], c);
            c = mfma16(aq1, *(const b16x8*)&Ks[buf][(ct * 2 + 1) * 512 + lane * 8], c);
            const int key = kt * 64 + ct * 16 + lq;
#pragma unroll
            for (int r = 0; r < 4; ++r) {
                float w = uni ? 1.0f : __expf(c[r] * 0.125f);
                w = (key < Leff) ? w : 0.0f;
                lp[r] += w;
                // P element (q=quad*4+r, k=ct*16+lq) -> A-frag layout
                Ps[wave][(ct >> 1) * 512 +
                         (((ct * 2 + (lq >> 3)) & 3) * 16 + quad * 4 + r) * 8 +
                         (lq & 7)] = (__bf16)w;
            }
        }
        // Ps is per-wave: in-wave lgkmcnt ordering suffices, no barrier.
        const b16x8 ap0 = *(const b16x8*)&Ps[wave][0   + lane * 8];
        const b16x8 ap1 = *(const b16x8*)&Ps[wave][512 + lane * 8];
#pragma unroll
        for (int ds = 0; ds < 4; ++ds) {
            o[ds] = mfma16(ap0, *(const b16x8*)&Vs[buf][(ds * 2 + 0) * 512 + lane * 8], o[ds]);
            o[ds] = mfma16(ap1, *(const b16x8*)&Vs[buf][(ds * 2 + 1) * 512 + lane * 8], o[ds]);
        }
        __syncthreads();                   // t+1 loads landed; buf reusable
        buf ^= 1;
    }

    float inv[4];
#pragma unroll
    for (int r = 0; r < 4; ++r) {
        float l = lp[r];
        l += __shfl_xor(l, 1); l += __shfl_xor(l, 2);
        l += __shfl_xor(l, 4); l += __shfl_xor(l, 8);
        inv[r] = 1.0f / l;
    }

    const int qrow = qg * 64 + wave * 16 + quad * 4;
#pragma unroll
    for (int ds = 0; ds < 4; ++ds)
#pragma unroll
        for (int r = 0; r < 4; ++r)
            O[((size_t)b * SS + qrow + r) * DD + ds * 16 + lq] = o[ds][r] * inv[r];

    // ---- Phase 2: W (transposed: S^T = mfma(K,Q), rows=keys, cols=q) ----
    const int  nt2   = uni ? 0 : ntiles;
    const int  kfill = nt2 * 64;
    const float fillv = uni ? (1.0f / 2048.0f) : 0.0f;

    // Rebroadcast inv from (quad,r)-indexed to lq-indexed via per-wave LDS
    // (Ps is free now; visibility via the barrier below).
    float* invs = (float*)&Ps[wave][0];
    if (lq == 0) {
#pragma unroll
        for (int r = 0; r < 4; ++r) invs[quad * 4 + r] = inv[r];
    }

    if (nt2 > 0) {
        buf = 0;
        stageK(0, 0);
        __syncthreads();                   // tile 0 ready + invs visible
        const float invq = invs[lq];       // inv for q-row wave*16+lq
        float* wrow = W + ((size_t)b * SS + qg * 64 + wave * 16 + lq) * SS;
        for (int kt = 0; kt < nt2; ++kt) {
            if (kt + 1 < nt2) stageK(kt + 1, buf ^ 1);
#pragma unroll
            for (int ct = 0; ct < 4; ++ct) {
                f32x4 c = (f32x4){0.f, 0.f, 0.f, 0.f};
                // swapped operands: A=K frag (rows=keys), B=Q frag (cols=q)
                c = mfma16(*(const b16x8*)&Ks[buf][(ct * 2 + 0) * 512 + lane * 8], aq0, c);
                c = mfma16(*(const b16x8*)&Ks[buf][(ct * 2 + 1) * 512 + lane * 8], aq1, c);
                const int key0 = kt * 64 + ct * 16 + quad * 4;
                f32x4 f;
                f[0] = (key0 + 0 < L) ? __expf(c[0] * 0.125f) * invq : 0.0f;
                f[1] = (key0 + 1 < L) ? __expf(c[1] * 0.125f) * invq : 0.0f;
                f[2] = (key0 + 2 < L) ? __expf(c[2] * 0.125f) * invq : 0.0f;
                f[3] = (key0 + 3 < L) ? __expf(c[3] * 0.125f) * invq : 0.0f;
                __builtin_nontemporal_store(f, (f32x4*)(wrow + key0));
            }
            __syncthreads();
            buf ^= 1;
        }
    }

    // fill masked tail [kfill, 2048) with fillv
    const f32x4 fv = (f32x4){fillv, fillv, fillv, fillv};
    for (int row = 0; row < 64; ++row) {
        float* base = W + ((size_t)b * SS + qg * 64 + row) * SS;
        for (int c = kfill + t * 4; c < SS; c += 1024)
            __builtin_nontemporal_store(fv, (f32x4*)(base + c));
    }
}

// ---------------------------------------------------------------------------
// Fallback path (ws too small): round-2 verified two-kernel design, verbatim.
// ---------------------------------------------------------------------------
__global__ __launch_bounds__(256)
void attn_o_kernel(const float* __restrict__ Q, const float* __restrict__ K,
                   const float* __restrict__ V, const int* __restrict__ VL,
                   float* __restrict__ O, float* __restrict__ W)
{
    __shared__ __align__(16) __bf16 Qs[4096], Ks[4096], Vs[4096];
    __shared__ __align__(16) __bf16 Ps[4][1024];

    const int t = threadIdx.x, lane = t & 63, wave = t >> 6;
    const int quad = lane >> 4, lq = lane & 15;
    const int b = blockIdx.x >> 5, qg = blockIdx.x & 31;

    const int  L    = VL[b];
    const bool uni  = (L == 0);
    const int  Leff = uni ? SS : L;
    const int  ntiles = (Leff + 63) >> 6;

    stage64x64(Q + ((size_t)b * SS + qg * 64) * DD, Qs, t);
    __syncthreads();

    const b16x8 aq0 = *(const b16x8*)&Qs[(wave * 2 + 0) * 512 + lane * 8];
    const b16x8 aq1 = *(const b16x8*)&Qs[(wave * 2 + 1) * 512 + lane * 8];

    f32x4 o[4];
#pragma unroll
    for (int d = 0; d < 4; ++d) o[d] = (f32x4){0.f, 0.f, 0.f, 0.f};
    float lp[4] = {0.f, 0.f, 0.f, 0.f};

    for (int kt = 0; kt < ntiles; ++kt) {
        const int kb = kt * 64;
        __syncthreads();
        stage64x64 (K + ((size_t)b * SS + kb) * DD, Ks, t);
        stageV64x64(V + ((size_t)b * SS + kb) * DD, Vs, t);
        __syncthreads();

#pragma unroll
        for (int ct = 0; ct < 4; ++ct) {
            f32x4 c = (f32x4){0.f, 0.f, 0.f, 0.f};
            c = mfma16(aq0, *(const b16x8*)&Ks[(ct * 2 + 0) * 512 + lane * 8], c);
            c = mfma16(aq1, *(const b16x8*)&Ks[(ct * 2 + 1) * 512 + lane * 8], c);
            const int key = kb + ct * 16 + lq;
#pragma unroll
            for (int r = 0; r < 4; ++r) {
                float w = uni ? 1.0f : __expf(c[r] * 0.125f);
                w = (key < Leff) ? w : 0.0f;
                lp[r] += w;
                Ps[wave][(ct >> 1) * 512 +
                         (((ct * 2 + (lq >> 3)) & 3) * 16 + quad * 4 + r) * 8 +
                         (lq & 7)] = (__bf16)w;
            }
        }
        __syncthreads();

        const b16x8 ap0 = *(const b16x8*)&Ps[wave][0   + lane * 8];
        const b16x8 ap1 = *(const b16x8*)&Ps[wave][512 + lane * 8];
#pragma unroll
        for (int ds = 0; ds < 4; ++ds) {
            o[ds] = mfma16(ap0, *(const b16x8*)&Vs[(ds * 2 + 0) * 512 + lane * 8], o[ds]);
            o[ds] = mfma16(ap1, *(const b16x8*)&Vs[(ds * 2 + 1) * 512 + lane * 8], o[ds]);
        }
    }

    float inv[4];
#pragma unroll
    for (int r = 0; r < 4; ++r) {
        float l = lp[r];
        l += __shfl_xor(l, 1); l += __shfl_xor(l, 2);
        l += __shfl_xor(l, 4); l += __shfl_xor(l, 8);
        inv[r] = 1.0f / l;
    }

    const int qrow = qg * 64 + wave * 16 + quad * 4;
#pragma unroll
    for (int ds = 0; ds < 4; ++ds)
#pragma unroll
        for (int r = 0; r < 4; ++r)
            O[((size_t)b * SS + qrow + r) * DD + ds * 16 + lq] = o[ds][r] * inv[r];

    if (lq == 0) {
#pragma unroll
        for (int r = 0; r < 4; ++r)
            W[((size_t)b * SS + qrow + r) * SS + (SS - 1)] = inv[r];
    }
}

__global__ __launch_bounds__(256)
void attn_w_kernel(const float* __restrict__ Q, const float* __restrict__ K,
                   const int* __restrict__ VL, float* __restrict__ W)
{
    __shared__ __align__(16) __bf16 Qs[4096], Ks[4096];

    const int t = threadIdx.x, lane = t & 63, wave = t >> 6;
    const int quad = lane >> 4, lq = lane & 15;
    const int b = blockIdx.x >> 5, qg = blockIdx.x & 31;

    const int  L   = VL[b];
    const bool uni = (L == 0);
    const int  ntiles = uni ? 0 : (L + 63) >> 6;
    const int  kfill  = ntiles * 64;
    const float fillv = uni ? (1.0f / 2048.0f) : 0.0f;
    const int  qrow = qg * 64 + wave * 16 + quad * 4;

    float inv[4] = {0.f, 0.f, 0.f, 0.f};
    if (!uni) {
#pragma unroll
        for (int r = 0; r < 4; ++r)
            inv[r] = W[((size_t)b * SS + qrow + r) * SS + (SS - 1)];
    }

    stage64x64(Q + ((size_t)b * SS + qg * 64) * DD, Qs, t);
    __syncthreads();

    const b16x8 aq0 = *(const b16x8*)&Qs[(wave * 2 + 0) * 512 + lane * 8];
    const b16x8 aq1 = *(const b16x8*)&Qs[(wave * 2 + 1) * 512 + lane * 8];

    for (int kt = 0; kt < ntiles; ++kt) {
        const int kb = kt * 64;
        __syncthreads();
        stage64x64(K + ((size_t)b * SS + kb) * DD, Ks, t);
        __syncthreads();

#pragma unroll
        for (int ct = 0; ct < 4; ++ct) {
            f32x4 c = (f32x4){0.f, 0.f, 0.f, 0.f};
            c = mfma16(aq0, *(const b16x8*)&Ks[(ct * 2 + 0) * 512 + lane * 8], c);
            c = mfma16(aq1, *(const b16x8*)&Ks[(ct * 2 + 1) * 512 + lane * 8], c);
            const int key = kb + ct * 16 + lq;
#pragma unroll
            for (int r = 0; r < 4; ++r) {
                float w = __expf(c[r] * 0.125f) * inv[r];
                w = (key < L) ? w : 0.0f;
                W[((size_t)b * SS + qrow + r) * SS + key] = w;
            }
        }
    }

    for (int row = 0; row < 64; ++row) {
        float* base = W + ((size_t)b * SS + qg * 64 + row) * SS;
        for (int c = kfill + t * 4; c < SS; c += 1024)
            *(float4*)(base + c) = make_float4(fillv, fillv, fillv, fillv);
    }
}

extern "C" void kernel_launch(void* const* d_in, const int* in_sizes, int n_in,
                              void* d_out, int out_size, void* d_ws, size_t ws_size,
                              hipStream_t stream) {
    const float* Q  = (const float*)d_in[0];
    const float* K  = (const float*)d_in[1];
    const float* V  = (const float*)d_in[2];
    const int*   VL = (const int*)d_in[3];
    float* O = (float*)d_out;
    float* W = (float*)d_out + (size_t)BB * SS * DD;

    const size_t nElem = (size_t)BB * SS * DD;          // 4,194,304
    const size_t need  = nElem * 2 * 3;                 // 24 MiB bf16 Q/K/V

    if (d_ws != nullptr && ws_size >= need) {
        __bf16* Qb = (__bf16*)d_ws;
        __bf16* Kb = Qb + nElem;
        __bf16* Vb = Kb + nElem;
        dim3 grid(BB * (SS / 64)), block(256);
        convert_kernel<<<grid, block, 0, stream>>>(Q, K, V, Qb, Kb, Vb);
        attn_fused<<<grid, block, 0, stream>>>(Qb, Kb, Vb, VL, O, W);
    } else {
        dim3 grid(BB * (SS / 64)), block(256);
        attn_o_kernel<<<grid, block, 0, stream>>>(Q, K, V, VL, O, W);
        attn_w_kernel<<<grid, block, 0, stream>>>(Q, K, VL, W);
    }
}